// Round 1
// baseline (76.317 us; speedup 1.0000x reference)
//
#include <hip/hip_runtime.h>

// Indexed segmented linear:
//   segments (mi, mo, d): (96,96,1), (64,64,3), (32,32,5)
//   x   row layout: [seg0: 96][seg1: 64*3=192][seg2: 32*5=160]  (i-major, m-minor)
//   out row layout: [seg0: 96][seg1: 64*3=192][seg2: 32*5=160]  (o-major, m-minor)
//   W[e] layout:    [seg0: 96*96=9216][seg1: 64*64=4096][seg2: 32*32=1024] (i-major, o-minor)
//   y[b, o*d+m] = sum_i x[b, i*d+m] * W[idx[b], i*mo+o]

#define BATCH     16384
#define IN_SIZE   448
#define OUT_SIZE  448
#define W_SIZE    14336

__global__ __launch_bounds__(448) void seglinear_f32_kernel(
    const float* __restrict__ weights,
    const float* __restrict__ x,
    const int*   __restrict__ widx,
    float*       __restrict__ out)
{
    __shared__ float xs[IN_SIZE];

    const int row = blockIdx.x;
    const int t   = threadIdx.x;

    const int e = widx[row];
    const float* __restrict__ W = weights + e * W_SIZE;

    // stage x row into LDS (coalesced; 448 threads load 448 floats)
    xs[t] = x[row * IN_SIZE + t];
    __syncthreads();

    float acc = 0.0f;

    if (t < 96) {
        // segment 0: mi=96, mo=96, d=1 ; o = t, m = 0
        const float* __restrict__ Wp = W + t;          // W[0 + i*96 + o]
        #pragma unroll
        for (int i = 0; i < 96; ++i)
            acc = fmaf(xs[i], Wp[i * 96], acc);
    } else if (t < 288) {
        // segment 1: mi=64, mo=64, d=3 ; rel = o*3+m
        const int rel = t - 96;
        const int o   = rel / 3;
        const int m   = rel - o * 3;
        const float* __restrict__ Wp = W + 9216 + o;   // W[9216 + i*64 + o]
        const float* __restrict__ xp = xs + 96 + m;    // x[96 + i*3 + m]
        #pragma unroll
        for (int i = 0; i < 64; ++i)
            acc = fmaf(xp[i * 3], Wp[i * 64], acc);
    } else {
        // segment 2: mi=32, mo=32, d=5 ; rel = o*5+m
        const int rel = t - 288;
        const int o   = rel / 5;
        const int m   = rel - o * 5;
        const float* __restrict__ Wp = W + 13312 + o;  // W[13312 + i*32 + o]
        const float* __restrict__ xp = xs + 288 + m;   // x[288 + i*5 + m]
        #pragma unroll
        for (int i = 0; i < 32; ++i)
            acc = fmaf(xp[i * 5], Wp[i * 32], acc);
    }

    out[row * OUT_SIZE + t] = acc;
}

extern "C" void kernel_launch(void* const* d_in, const int* in_sizes, int n_in,
                              void* d_out, int out_size, void* d_ws, size_t ws_size,
                              hipStream_t stream) {
    const float* weights = (const float*)d_in[0];   // [64, 14336] f32
    const float* x       = (const float*)d_in[1];   // [16384, 448] f32
    const int*   widx    = (const int*)d_in[2];     // [16384] int
    float*       out     = (float*)d_out;           // [16384, 448] f32

    seglinear_f32_kernel<<<BATCH, 448, 0, stream>>>(weights, x, widx, out);
}